// Round 10
// baseline (1826.097 us; speedup 1.0000x reference)
//
#include <hip/hip_runtime.h>

#define TT 2048
#define II 64
#define HH 256
#define MPB 16    // batches per block -> 4 blocks
#define PSTR 17   // part row stride (floats), odd -> conflict-free final reads

typedef __fp16 f16x8 __attribute__((ext_vector_type(8)));
typedef float  f32x4 __attribute__((ext_vector_type(4)));

#define MFMA(a, b, c) __builtin_amdgcn_mfma_f32_16x16x32_f16((a), (b), (c), 0, 0, 0)

// pack 8 fp32 -> f16x8 fragment
__device__ __forceinline__ f16x8 pack8(float4 a, float4 b) {
    int4 iv;
    iv.x = __builtin_bit_cast(int, __builtin_amdgcn_cvt_pkrtz(a.x, a.y));
    iv.y = __builtin_bit_cast(int, __builtin_amdgcn_cvt_pkrtz(a.z, a.w));
    iv.z = __builtin_bit_cast(int, __builtin_amdgcn_cvt_pkrtz(b.x, b.y));
    iv.w = __builtin_bit_cast(int, __builtin_amdgcn_cvt_pkrtz(b.z, b.w));
    return __builtin_bit_cast(f16x8, iv);
}

// tanh(x) = 1 - 2/(e^{2x}+1)
__device__ __forceinline__ float ftanh(float x) {
    float e = __expf(2.0f * x);
    return 1.0f - 2.0f * __builtin_amdgcn_rcpf(e + 1.0f);
}

// 4 blocks x 256 thr (4 waves, 1/SIMD, 512-VGPR budget for the pinned tile).
// Per step: D = W x h (operands SWAPPED vs R9): A = weight frags (m = hidden
// col), B = h/x frags (n = batch). A and B share the same physical lane
// layout, so the swap is free. Payoff: C values per thread are 4 CONSECUTIVE
// hidden units of one batch -> one packed ds_write_b64 per tile instead of
// R9's 16 scattered ds_write_b16 (R9's LDS write pipe was the floor).
// hbuf fragment-ready layout: (m_batch,k_hidden) at half-index
// (k>>5)*512 + ((k>>3)&3)*128 + m*8 + (k&7); lane l reads frag kb at
// kb*512 + l*8 -> dense 64x16B, conflict-free.
// Head: R8-style delayed MFMA on wave 0 (A = W_fc in row 0): out[i-1] lands
// in lanes 0-15, single writer per part[] element -> NO ATOMICS (R9's LDS
// float atomicAdd was the replay-nondeterminism suspect; removed).
__launch_bounds__(256, 1)
__global__ void rnn_mfma(const float* __restrict__ x,
                         const float* __restrict__ W_ih,
                         const float* __restrict__ W_hh,
                         const float* __restrict__ b_ih,
                         const float* __restrict__ b_hh,
                         const float* __restrict__ W_fc,
                         const float* __restrict__ b_fc,
                         float* __restrict__ out) {
    __shared__ __align__(16) __fp16 hbuf[2][4096];  // 16 KB double-buffered h
    __shared__ float part[TT * PSTR];               // head results (no init needed)

    const int tid  = threadIdx.x;
    const int b0   = blockIdx.x;
    const int lane = tid & 63;
    const int w    = tid >> 6;   // wave 0..3 -> hidden cols [w*64, w*64+64)
    const int nl   = lane & 15;  // A: hidden-col-in-tile / B,C: batch
    const int g    = lane >> 4;  // k-subgroup / C row-group
    const int g2   = g * 2;

    // ---- A-fragments (weights), pinned; bias per (tt, r) ----
    f16x8 wb[4][10];
    f32x4 biasv[4];
#pragma unroll
    for (int tt = 0; tt < 4; ++tt) {
        const int col = w * 64 + tt * 16 + nl;  // weight row for A m=nl
        const float* wrow = W_hh + col * HH + g * 8;
#pragma unroll
        for (int kb = 0; kb < 8; ++kb) {
            const float4* p = (const float4*)(wrow + kb * 32);
            wb[tt][kb] = pack8(p[0], p[1]);
        }
        const float* irow = W_ih + col * II + g * 8;
        { const float4* p = (const float4*)irow;        wb[tt][8] = pack8(p[0], p[1]); }
        { const float4* p = (const float4*)(irow + 32); wb[tt][9] = pack8(p[0], p[1]); }
#pragma unroll
        for (int r = 0; r < 4; ++r) {
            const int hc = w * 64 + tt * 16 + g * 4 + r;  // C row -> hidden col
            biasv[tt][r] = b_ih[hc] + b_hh[hc];
        }
    }
#pragma unroll
    for (int tt = 0; tt < 4; ++tt)
#pragma unroll
        for (int kb = 0; kb < 10; ++kb) asm volatile("" : "+v"(wb[tt][kb]));

    // head A-fragment (wave 0): A row 0 = W_fc, rows 1-15 zero
    const f16x8 z8 = {0, 0, 0, 0, 0, 0, 0, 0};
    f16x8 whd[8];
#pragma unroll
    for (int kb = 0; kb < 8; ++kb) whd[kb] = z8;
    if (w == 0) {
        if (nl == 0) {
#pragma unroll
            for (int kb = 0; kb < 8; ++kb) {
                const float4* pf = (const float4*)(W_fc + kb * 32 + g * 8);
                whd[kb] = pack8(pf[0], pf[1]);
            }
        }
#pragma unroll
        for (int kb = 0; kb < 8; ++kb) asm volatile("" : "+v"(whd[kb]));
    }

    const float bfc = b_fc[0];

    for (int idx = tid; idx < 2 * 4096; idx += 256) ((__fp16*)hbuf)[idx] = (__fp16)0.0f;
    __syncthreads();

    const __fp16* hrd = (const __fp16*)hbuf + lane * 8;  // B-frag read base
    __fp16* hba = (__fp16*)hbuf;
    // packed b64 write base per tile (halfs); r is packed in-register
    int wb64[4];
#pragma unroll
    for (int tt = 0; tt < 4; ++tt)
        wb64[tt] = (2 * w + (tt >> 1)) * 512 + (2 * (tt & 1) + (g >> 1)) * 128
                 + nl * 8 + (g & 1) * 4;

    const float* xrow = x + (size_t)(b0 * MPB + nl) * TT * II;
    float4 xa0, xa1, xb0, xb1;
    {
        const float4* xp = (const float4*)xrow + g2;        xa0 = xp[0]; xa1 = xp[1];
        const float4* xq = (const float4*)(xrow + 32) + g2; xb0 = xq[0]; xb1 = xq[1];
    }

#define STEP(i, P) do {                                                          \
    f16x8 af[10];                                                                \
    af[8] = pack8(xa0, xa1);                                                     \
    af[9] = pack8(xb0, xb1);                                                     \
    { const float* xn = xrow + (size_t)(((i) + 1 < TT) ? (i) + 1 : (i)) * II;    \
      const float4* xp = (const float4*)xn + g2;        xa0 = xp[0]; xa1 = xp[1];\
      const float4* xq = (const float4*)(xn + 32) + g2; xb0 = xq[0]; xb1 = xq[1];}\
    _Pragma("unroll")                                                            \
    for (int kb = 0; kb < 8; ++kb)                                               \
        af[kb] = *(const f16x8*)(hrd + (P) * 4096 + kb * 512);                   \
    f32x4 c[4], cb[4];                                                           \
    _Pragma("unroll")                                                            \
    for (int tt = 0; tt < 4; ++tt) { c[tt] = biasv[tt]; cb[tt] = (f32x4){0,0,0,0}; } \
    _Pragma("unroll")                                                            \
    for (int kk = 0; kk < 5; ++kk) {                                             \
        _Pragma("unroll")                                                        \
        for (int tt = 0; tt < 4; ++tt) c[tt]  = MFMA(wb[tt][2*kk],   af[2*kk],   c[tt]);  \
        _Pragma("unroll")                                                        \
        for (int tt = 0; tt < 4; ++tt) cb[tt] = MFMA(wb[tt][2*kk+1], af[2*kk+1], cb[tt]); \
    }                                                                            \
    if (w == 0) { /* delayed head: out[i-1] = h_i . W_fc, single writer */       \
        f32x4 ch = {0, 0, 0, 0};                                                 \
        _Pragma("unroll")                                                        \
        for (int kb = 0; kb < 8; ++kb) ch = MFMA(whd[kb], af[kb], ch);           \
        if (lane < 16 && (i) > 0) part[((i) - 1) * PSTR + nl] = ch[0];           \
    }                                                                            \
    _Pragma("unroll")                                                            \
    for (int tt = 0; tt < 4; ++tt) {                                             \
        const float h0 = ftanh(c[tt][0] + cb[tt][0]);                            \
        const float h1 = ftanh(c[tt][1] + cb[tt][1]);                            \
        const float h2 = ftanh(c[tt][2] + cb[tt][2]);                            \
        const float h3 = ftanh(c[tt][3] + cb[tt][3]);                            \
        int2 pk;                                                                 \
        pk.x = __builtin_bit_cast(int, __builtin_amdgcn_cvt_pkrtz(h0, h1));      \
        pk.y = __builtin_bit_cast(int, __builtin_amdgcn_cvt_pkrtz(h2, h3));      \
        *(int2*)(hba + ((P) ^ 1) * 4096 + wb64[tt]) = pk;                        \
    }                                                                            \
    __syncthreads();                                                             \
} while (0)

    for (int i = 0; i < TT; i += 2) {
        STEP(i, 0);
        STEP(i + 1, 1);
    }
#undef STEP

    // epilogue: out[TT-1] needs h_TT (in buffer 0) . W_fc
    if (w == 0) {
        f16x8 ef[8];
#pragma unroll
        for (int kb = 0; kb < 8; ++kb) ef[kb] = *(const f16x8*)(hrd + kb * 512);
        f32x4 ch = {0, 0, 0, 0};
#pragma unroll
        for (int kb = 0; kb < 8; ++kb) ch = MFMA(whd[kb], ef[kb], ch);
        if (lane < 16) part[(TT - 1) * PSTR + nl] = ch[0];
    }
    __syncthreads();

    // out[b][t] = part[t][m] + bfc; consecutive tid -> consecutive t
    for (int idx = tid; idx < MPB * TT; idx += 256) {
        const int m = idx >> 11;
        const int t = idx & (TT - 1);
        out[(size_t)(b0 * MPB + m) * TT + t] = part[t * PSTR + m] + bfc;
    }
}

extern "C" void kernel_launch(void* const* d_in, const int* in_sizes, int n_in,
                              void* d_out, int out_size, void* d_ws, size_t ws_size,
                              hipStream_t stream) {
    const float* x    = (const float*)d_in[0];
    const float* W_ih = (const float*)d_in[1];
    const float* W_hh = (const float*)d_in[2];
    const float* b_ih = (const float*)d_in[3];
    const float* b_hh = (const float*)d_in[4];
    const float* W_fc = (const float*)d_in[5];
    const float* b_fc = (const float*)d_in[6];
    float* out = (float*)d_out;

    rnn_mfma<<<64 / MPB, 256, 0, stream>>>(x, W_ih, W_hh, b_ih, b_hh, W_fc, b_fc, out);
}